// Round 3
// baseline (547.020 us; speedup 1.0000x reference)
//
#include <hip/hip_runtime.h>

#define MM 2048   // memory slots
#define BB 64     // batch
#define TT 4      // tokens per slot
#define DD 128    // embed dim
#define VV 50000  // vocab
#define VPAD 50176  // VV rounded up to multiple of 256

// ---- zero u ----
__global__ void k_zero(float* __restrict__ u) {
    u[blockIdx.x * 256 + threadIdx.x] = 0.f;
}

// ---- zero W (float4 per thread) ----
__global__ void k_zero_w(float* __restrict__ w) {
    const int i = blockIdx.x * 256 + threadIdx.x;
    *(float4*)(w + (size_t)i * 4) = make_float4(0.f, 0.f, 0.f, 0.f);
}

// ---- GEMM1: P[v][b] = dot(C[h][v], u[b]) ----
// block 256 thr, v-tile 32. thread: vg = t>>3 (one v), b0 = (t&7)*8 (8 b's).
// LDS: u transposed [d][b] 32 KB + C tile [32][132] 16.9 KB (pad for banks).
__global__ __launch_bounds__(256) void k_gemm_p(const float* __restrict__ Ch,
                                                const float* __restrict__ u,
                                                float* __restrict__ P) {
    __shared__ float lds_u[DD * BB];   // [d][b]
    __shared__ float lds_c[32 * 132];  // [v][d], stride 132
    const int t = threadIdx.x;
    const int v0 = blockIdx.x * 32;

    // stage u transposed: 8192 floats / 256 thr = 32 each
#pragma unroll
    for (int k = 0; k < 32; ++k) {
        const int f = k * 256 + t;  // f = b*128 + d
        lds_u[(f & 127) * 64 + (f >> 7)] = u[f];
    }
    // stage C tile: 32*128 floats, float4 x 4 per thread
#pragma unroll
    for (int k = 0; k < 4; ++k) {
        const int f = (k * 256 + t) * 4;  // 0..4095
        const int vl = f >> 7, d = f & 127;
        const int v = v0 + vl;
        float4 val = (v < VV) ? *(const float4*)(Ch + (size_t)v * DD + d)
                              : make_float4(0.f, 0.f, 0.f, 0.f);
        *(float4*)&lds_c[vl * 132 + d] = val;
    }
    __syncthreads();

    const int vg = t >> 3;
    const int b0 = (t & 7) * 8;
    float acc[8] = {0.f, 0.f, 0.f, 0.f, 0.f, 0.f, 0.f, 0.f};
#pragma unroll 4
    for (int d = 0; d < DD; ++d) {
        const float c = lds_c[vg * 132 + d];
        const float4 ua = *(const float4*)&lds_u[d * 64 + b0];
        const float4 ub = *(const float4*)&lds_u[d * 64 + b0 + 4];
        acc[0] += c * ua.x; acc[1] += c * ua.y;
        acc[2] += c * ua.z; acc[3] += c * ua.w;
        acc[4] += c * ub.x; acc[5] += c * ub.y;
        acc[6] += c * ub.z; acc[7] += c * ub.w;
    }
    const int v = v0 + vg;
    if (v < VV) {
        float4* dst = (float4*)(P + (size_t)v * 64 + b0);
        dst[0] = make_float4(acc[0], acc[1], acc[2], acc[3]);
        dst[1] = make_float4(acc[4], acc[5], acc[6], acc[7]);
    }
}

// ---- gather scores: s[m*64+b] = sum_t (tok!=0) P[tok*64+b] ----
__global__ __launch_bounds__(256) void k_gather(const int* __restrict__ st,
                                                const float* __restrict__ P,
                                                float* __restrict__ s) {
    const int g = blockIdx.x * 256 + threadIdx.x;  // g = m*64+b
    const int b = g & 63;
    const int4 tk = *(const int4*)(st + (size_t)g * 4);
    float acc = 0.f;
    if (tk.x) acc += P[(size_t)tk.x * 64 + b];
    if (tk.y) acc += P[(size_t)tk.y * 64 + b];
    if (tk.z) acc += P[(size_t)tk.z * 64 + b];
    if (tk.w) acc += P[(size_t)tk.w * 64 + b];
    s[g] = acc;
}

// ---- softmax over m for each b; s layout [m][b] ----
__global__ __launch_bounds__(256) void k_softmax(float* __restrict__ s) {
    const int b = blockIdx.x;
    const int tid = threadIdx.x;  // 256
    __shared__ float redmax[4];
    __shared__ float redsum[4];

    float v[8];
    float mx = -1e30f;
#pragma unroll
    for (int i = 0; i < 8; ++i) {
        v[i] = s[(size_t)(tid + 256 * i) * 64 + b];
        mx = fmaxf(mx, v[i]);
    }
#pragma unroll
    for (int off = 32; off; off >>= 1) mx = fmaxf(mx, __shfl_xor(mx, off, 64));
    if ((tid & 63) == 0) redmax[tid >> 6] = mx;
    __syncthreads();
    const float gmax = fmaxf(fmaxf(redmax[0], redmax[1]),
                             fmaxf(redmax[2], redmax[3]));

    float sum = 0.f;
#pragma unroll
    for (int i = 0; i < 8; ++i) {
        v[i] = __expf(v[i] - gmax);
        sum += v[i];
    }
#pragma unroll
    for (int off = 32; off; off >>= 1) sum += __shfl_xor(sum, off, 64);
    if ((tid & 63) == 0) redsum[tid >> 6] = sum;
    __syncthreads();
    const float inv = 1.f / (redsum[0] + redsum[1] + redsum[2] + redsum[3]);
#pragma unroll
    for (int i = 0; i < 8; ++i)
        s[(size_t)(tid + 256 * i) * 64 + b] = v[i] * inv;
}

// ---- scatter: W[tok*64+b] += prob[m,b] for each non-pad token ----
__global__ __launch_bounds__(256) void k_scatter(const int* __restrict__ st,
                                                 const float* __restrict__ s,
                                                 float* __restrict__ W) {
    const int g = blockIdx.x * 256 + threadIdx.x;  // g = m*64+b
    const int b = g & 63;
    const float p = s[g];
    const int4 tk = *(const int4*)(st + (size_t)g * 4);
    if (tk.x) atomicAdd(W + (size_t)tk.x * 64 + b, p);
    if (tk.y) atomicAdd(W + (size_t)tk.y * 64 + b, p);
    if (tk.z) atomicAdd(W + (size_t)tk.z * 64 + b, p);
    if (tk.w) atomicAdd(W + (size_t)tk.w * 64 + b, p);
}

// ---- GEMM2: u[b][d] += sum_v W[v][b] * C2[v][d] ----
// block 256 thr handles v-chunk of 256 (4 staged sub-chunks of 64).
// thread: d = t&127, bh = t>>7 -> 32 b's. acc[32]. atomicAdd epilogue into u.
__global__ __launch_bounds__(256) void k_gemm_o(const float* __restrict__ C2,
                                                const float* __restrict__ W,
                                                float* __restrict__ u) {
    __shared__ float lds_c[64 * DD];  // 32 KB
    __shared__ float lds_w[64 * BB];  // 16 KB
    const int t = threadIdx.x;
    const int d = t & 127;
    const int bh = t >> 7;
    const int vbase = blockIdx.x * 256;

    float acc[32];
#pragma unroll
    for (int j = 0; j < 32; ++j) acc[j] = 0.f;

    for (int cc = 0; cc < 4; ++cc) {
        const int vc = vbase + cc * 64;
        // stage C2 tile: 64x128 floats, float4 x 8 per thread (guard v<VV)
#pragma unroll
        for (int k = 0; k < 8; ++k) {
            const int f = (k * 256 + t) * 4;  // 0..8191
            const int vl = f >> 7, dd = f & 127;
            const int v = vc + vl;
            float4 val = (v < VV) ? *(const float4*)(C2 + (size_t)v * DD + dd)
                                  : make_float4(0.f, 0.f, 0.f, 0.f);
            *(float4*)&lds_c[f] = val;
        }
        // stage W tile: 64x64 floats (W is VPAD rows, zeroed -> no guard)
#pragma unroll
        for (int k = 0; k < 4; ++k) {
            const int f = (k * 256 + t) * 4;
            *(float4*)&lds_w[f] = *(const float4*)(W + (size_t)vc * 64 + f);
        }
        __syncthreads();

        for (int vl = 0; vl < 64; ++vl) {
            const float c = lds_c[vl * 128 + d];
            const float4* wrow = (const float4*)&lds_w[vl * 64 + bh * 32];
#pragma unroll
            for (int j4 = 0; j4 < 8; ++j4) {
                const float4 w4 = wrow[j4];
                acc[j4 * 4 + 0] += c * w4.x;
                acc[j4 * 4 + 1] += c * w4.y;
                acc[j4 * 4 + 2] += c * w4.z;
                acc[j4 * 4 + 3] += c * w4.w;
            }
        }
        __syncthreads();
    }
#pragma unroll
    for (int j = 0; j < 32; ++j)
        atomicAdd(u + (size_t)(bh * 32 + j) * DD + d, acc[j]);
}

// ---- copy u -> out ----
__global__ void k_copy(const float* __restrict__ u, float* __restrict__ out) {
    const int i = blockIdx.x * 256 + threadIdx.x;
    out[i] = u[i];
}

extern "C" void kernel_launch(void* const* d_in, const int* in_sizes, int n_in,
                              void* d_out, int out_size, void* d_ws, size_t ws_size,
                              hipStream_t stream) {
    const int* st = (const int*)d_in[0];
    const float* C = (const float*)d_in[1];

    float* u  = (float*)d_ws;            // 64*128 = 32 KB
    float* s  = u + BB * DD;             // 2048*64 = 512 KB, layout [m][b]
    float* PW = s + MM * BB;             // VPAD*64 fp32 = 12.85 MB (P and W share)

    k_zero<<<(BB * DD) / 256, 256, 0, stream>>>(u);

    for (int hop = 0; hop < 3; ++hop) {
        const float* Ch  = C + (size_t)hop * VV * DD;
        const float* Ch1 = C + (size_t)(hop + 1) * VV * DD;

        k_gemm_p<<<(VV + 31) / 32, 256, 0, stream>>>(Ch, u, PW);
        k_gather<<<(MM * BB) / 256, 256, 0, stream>>>(st, PW, s);
        k_softmax<<<BB, 256, 0, stream>>>(s);
        k_zero_w<<<(VPAD * BB / 4) / 256, 256, 0, stream>>>(PW);
        k_scatter<<<(MM * BB) / 256, 256, 0, stream>>>(st, s, PW);
        k_gemm_o<<<VPAD / 256, 256, 0, stream>>>(Ch1, PW, u);
    }

    k_copy<<<(BB * DD) / 256, 256, 0, stream>>>(u, (float*)d_out);
}